// Round 1
// baseline (117.824 us; speedup 1.0000x reference)
//
#include <hip/hip_runtime.h>
#include <math.h>

#define NB2   128
#define NT    1024
#define ND    1024
#define BHALF 64
#define NROWS (NB2 * NT)      // 131072 rows of feats / elements of scores
#define MARGIN_F 200.0f
#define EPS_F    1e-6f

// ws layout (float* view):
// [0] bce_acc  [1] loss_n_acc  [2] loss_a_acc  [3] min_d
// [4] i_star (int)  [5] j_star (int)
// [8 .. 8+4096)        d matrix (64x64)
// [8192 .. 8192+131072) mags (128 x 1024)

__device__ __forceinline__ float wave_reduce_sum(float s) {
#pragma unroll
    for (int off = 32; off > 0; off >>= 1)
        s += __shfl_xor(s, off, 64);
    return s;
}

// ---- Stage 1: mags[r] = sum_k |feats[r][k]| ; one wave per row ----
__global__ void mags_kernel(const float* __restrict__ feats,
                            float* __restrict__ mags) {
    const int wave = threadIdx.x >> 6;           // 0..3
    const int lane = threadIdx.x & 63;
    const int row  = blockIdx.x * 4 + wave;      // 0..131071
    const float* src = feats + (size_t)row * ND;
    float s = 0.0f;
#pragma unroll
    for (int it = 0; it < 4; ++it) {
        float4 v = *reinterpret_cast<const float4*>(src + lane * 4 + it * 256);
        s += fabsf(v.x) + fabsf(v.y) + fabsf(v.z) + fabsf(v.w);
    }
    s = wave_reduce_sum(s);
    if (lane == 0) mags[row] = s;
}

// ---- Stage 2: BCE-with-logits sum over all 131072 elements ----
__global__ void bce_kernel(const float* __restrict__ scores,
                           const float* __restrict__ targets,
                           float* __restrict__ ws) {
    const int idx = blockIdx.x * blockDim.x + threadIdx.x;   // 0..32767
    float4 l4 = reinterpret_cast<const float4*>(scores)[idx];
    float4 t4 = reinterpret_cast<const float4*>(targets)[idx];
    float s = 0.0f;
    {
        float l = l4.x, t = t4.x;
        s += fmaxf(l, 0.0f) - l * t + log1pf(expf(-fabsf(l)));
        l = l4.y; t = t4.y;
        s += fmaxf(l, 0.0f) - l * t + log1pf(expf(-fabsf(l)));
        l = l4.z; t = t4.z;
        s += fmaxf(l, 0.0f) - l * t + log1pf(expf(-fabsf(l)));
        l = l4.w; t = t4.w;
        s += fmaxf(l, 0.0f) - l * t + log1pf(expf(-fabsf(l)));
    }
    s = wave_reduce_sum(s);
    __shared__ float lds[4];
    const int wave = threadIdx.x >> 6;
    const int lane = threadIdx.x & 63;
    if (lane == 0) lds[wave] = s;
    __syncthreads();
    if (threadIdx.x == 0) {
        float b = lds[0] + lds[1] + lds[2] + lds[3];
        atomicAdd(&ws[0], b);
    }
}

// ---- Stage 3: d[i*64+j] = max(MARGIN - ||n_f[i]-a_f[j]+EPS||, 0)^2 ----
__global__ void dist_kernel(const float* __restrict__ mags,
                            float* __restrict__ dmat) {
    const int wave = threadIdx.x >> 6;
    const int lane = threadIdx.x & 63;
    const int pair = blockIdx.x * 4 + wave;      // 0..4095
    const int i = pair >> 6;
    const int j = pair & 63;
    const float* nf = mags + (size_t)i * NT;
    const float* af = mags + (size_t)(BHALF + j) * NT;
    float s = 0.0f;
#pragma unroll
    for (int it = 0; it < 4; ++it) {
        float4 a = *reinterpret_cast<const float4*>(nf + lane * 4 + it * 256);
        float4 b = *reinterpret_cast<const float4*>(af + lane * 4 + it * 256);
        float dx = a.x - b.x + EPS_F; s += dx * dx;
        dx = a.y - b.y + EPS_F; s += dx * dx;
        dx = a.z - b.z + EPS_F; s += dx * dx;
        dx = a.w - b.w + EPS_F; s += dx * dx;
    }
    s = wave_reduce_sum(s);
    if (lane == 0) {
        float dist = sqrtf(s);
        float m = MARGIN_F - dist;
        dmat[pair] = (m > 0.0f) ? m * m : 0.0f;
    }
}

// ---- Stage 4: argmin over 4096 entries, first-occurrence tie-break ----
__global__ void argmin_kernel(const float* __restrict__ dmat,
                              float* __restrict__ ws) {
    __shared__ float sv[256];
    __shared__ int   si[256];
    const int t = threadIdx.x;
    float best = INFINITY;
    int   bidx = 0x7FFFFFFF;
    for (int k = t; k < 4096; k += 256) {
        float v = dmat[k];
        if (v < best || (v == best && k < bidx)) { best = v; bidx = k; }
    }
    sv[t] = best; si[t] = bidx;
    __syncthreads();
    for (int s = 128; s > 0; s >>= 1) {
        if (t < s) {
            float v2 = sv[t + s]; int i2 = si[t + s];
            if (v2 < sv[t] || (v2 == sv[t] && i2 < si[t])) { sv[t] = v2; si[t] = i2; }
        }
        __syncthreads();
    }
    if (t == 0) {
        ws[3] = sv[0];
        int* wsi = reinterpret_cast<int*>(ws);
        wsi[4] = si[0] >> 6;   // i_star
        wsi[5] = si[0] & 63;   // j_star
    }
}

// ---- Stage 5: loss_n / loss_a row sums vs the argmin rows ----
__global__ void lossna_kernel(const float* __restrict__ mags,
                              float* __restrict__ ws) {
    const int gwave = (blockIdx.x * blockDim.x + threadIdx.x) >> 6;  // 0..127
    const int lane  = threadIdx.x & 63;
    const int* wsi  = reinterpret_cast<const int*>(ws);
    const int istar = wsi[4];
    const int jstar = wsi[5];

    int row, ref, accslot;
    if (gwave < BHALF) {
        row = gwave; ref = istar; accslot = 1;
        if (row == istar) return;                 // excluded: sum - sq[i_star]
    } else {
        row = gwave; ref = BHALF + jstar; accslot = 2;
        if (gwave - BHALF == jstar) return;
    }
    const float* r0 = mags + (size_t)row * NT;
    const float* r1 = mags + (size_t)ref * NT;
    float s = 0.0f;
#pragma unroll
    for (int it = 0; it < 4; ++it) {
        float4 a = *reinterpret_cast<const float4*>(r0 + lane * 4 + it * 256);
        float4 b = *reinterpret_cast<const float4*>(r1 + lane * 4 + it * 256);
        float dx = a.x - b.x + EPS_F; s += dx * dx;
        dx = a.y - b.y + EPS_F; s += dx * dx;
        dx = a.z - b.z + EPS_F; s += dx * dx;
        dx = a.w - b.w + EPS_F; s += dx * dx;
    }
    s = wave_reduce_sum(s);
    if (lane == 0) atomicAdd(&ws[accslot], s);
}

// ---- Stage 6: combine ----
__global__ void finalize_kernel(const float* __restrict__ ws,
                                float* __restrict__ out) {
    float bce    = ws[0] / (float)NROWS;
    float loss_c = 0.001f * ws[3];
    float loss_n = ws[1] / (float)BHALF;
    float loss_a = ws[2] / (float)BHALF;
    out[0] = bce + 0.001f * (loss_c + loss_n + loss_a);
}

extern "C" void kernel_launch(void* const* d_in, const int* in_sizes, int n_in,
                              void* d_out, int out_size, void* d_ws, size_t ws_size,
                              hipStream_t stream) {
    const float* scores  = (const float*)d_in[0];
    const float* feats   = (const float*)d_in[1];
    const float* targets = (const float*)d_in[2];
    float* out  = (float*)d_out;
    float* ws   = (float*)d_ws;
    float* dmat = ws + 8;
    float* mags = ws + 8192;

    // zero the accumulators (harness does not re-poison between replays)
    hipMemsetAsync(d_ws, 0, 32, stream);

    mags_kernel  <<<NROWS / 4, 256, 0, stream>>>(feats, mags);
    bce_kernel   <<<NROWS / 4 / 256, 256, 0, stream>>>(scores, targets, ws);
    dist_kernel  <<<4096 / 4, 256, 0, stream>>>(mags, dmat);
    argmin_kernel<<<1, 256, 0, stream>>>(dmat, ws);
    lossna_kernel<<<128 * 64 / 256, 256, 0, stream>>>(mags, ws);
    finalize_kernel<<<1, 1, 0, stream>>>(ws, out);
}

// Round 2
// 98.293 us; speedup vs baseline: 1.1987x; 1.1987x over previous
//
#include <hip/hip_runtime.h>
#include <math.h>

typedef float f32x4 __attribute__((ext_vector_type(4)));

#define NB2   128
#define NT    1024
#define ND    1024
#define BHALF 64
#define NROWS (NB2 * NT)      // 131072
#define MARGIN_F 200.0f
#define EPS_F    1e-6f

#define MAGS_BLOCKS (NROWS / 4)   // 32768, one wave per row
#define BCE_BLOCKS  128           // 128 * 256 threads * 4 floats = 131072

// ws layout (float* view):
// [64 .. 192)            bce per-block partials (128)
// [1024 .. 5120)         d matrix (64x64)
// [8192 .. 8192+131072)  mags (128 x 1024)

__device__ __forceinline__ float wave_reduce_sum(float s) {
#pragma unroll
    for (int off = 32; off > 0; off >>= 1)
        s += __shfl_xor(s, off, 64);
    return s;
}

// ---- Stage 1: mags (one wave per row) + bce (tail blocks, partials) ----
__global__ void mags_bce_kernel(const float* __restrict__ feats,
                                const float* __restrict__ scores,
                                const float* __restrict__ targets,
                                float* __restrict__ mags,
                                float* __restrict__ bce_part) {
    const int wave = threadIdx.x >> 6;
    const int lane = threadIdx.x & 63;

    if (blockIdx.x < MAGS_BLOCKS) {
        const int row = blockIdx.x * 4 + wave;   // 0..131071
        const float* src = feats + (size_t)row * ND;
        float s = 0.0f;
#pragma unroll
        for (int it = 0; it < 4; ++it) {
            f32x4 v = __builtin_nontemporal_load(
                reinterpret_cast<const f32x4*>(src + lane * 4 + it * 256));
            s += fabsf(v.x) + fabsf(v.y) + fabsf(v.z) + fabsf(v.w);
        }
        s = wave_reduce_sum(s);
        if (lane == 0) mags[row] = s;
        return;
    }

    // ---- BCE blocks ----
    const int b   = blockIdx.x - MAGS_BLOCKS;        // 0..127
    const int idx = b * 256 + threadIdx.x;           // float4 index
    f32x4 l4 = reinterpret_cast<const f32x4*>(scores)[idx];
    f32x4 t4 = reinterpret_cast<const f32x4*>(targets)[idx];
    float s = 0.0f;
#pragma unroll
    for (int c = 0; c < 4; ++c) {
        float l = l4[c], t = t4[c];
        s += fmaxf(l, 0.0f) - l * t + log1pf(expf(-fabsf(l)));
    }
    s = wave_reduce_sum(s);
    __shared__ float lds[4];
    if (lane == 0) lds[wave] = s;
    __syncthreads();
    if (threadIdx.x == 0)
        bce_part[b] = lds[0] + lds[1] + lds[2] + lds[3];
}

// ---- Stage 2: d[i*64+j] = max(MARGIN - ||n_f[i]-a_f[j]+EPS||, 0)^2 ----
__global__ void dist_kernel(const float* __restrict__ mags,
                            float* __restrict__ dmat) {
    const int wave = threadIdx.x >> 6;
    const int lane = threadIdx.x & 63;
    const int pair = blockIdx.x * 4 + wave;      // 0..4095
    const int i = pair >> 6;
    const int j = pair & 63;
    const float* nf = mags + (size_t)i * NT;
    const float* af = mags + (size_t)(BHALF + j) * NT;
    float s = 0.0f;
#pragma unroll
    for (int it = 0; it < 4; ++it) {
        f32x4 a = *reinterpret_cast<const f32x4*>(nf + lane * 4 + it * 256);
        f32x4 b = *reinterpret_cast<const f32x4*>(af + lane * 4 + it * 256);
#pragma unroll
        for (int c = 0; c < 4; ++c) {
            float dx = a[c] - b[c] + EPS_F;
            s += dx * dx;
        }
    }
    s = wave_reduce_sum(s);
    if (lane == 0) {
        float dist = sqrtf(s);
        float m = MARGIN_F - dist;
        dmat[pair] = (m > 0.0f) ? m * m : 0.0f;
    }
}

// ---- Stage 3: argmin + loss_n/loss_a + finalize, single block ----
__global__ void __launch_bounds__(1024)
mega_kernel(const float* __restrict__ mags,
            const float* __restrict__ dmat,
            const float* __restrict__ bce_part,
            float* __restrict__ out) {
    __shared__ float sval[16];
    __shared__ int   sidx[16];
    __shared__ float bpart2[2];
    __shared__ float partials[16];
    __shared__ float s_mind;
    __shared__ int   s_istar, s_jstar;
    __shared__ float s_bce;

    const int t    = threadIdx.x;
    const int wave = t >> 6;
    const int lane = t & 63;

    // --- argmin over dmat[4096], first-occurrence tie-break ---
    float best = INFINITY;
    int   bidx = 0x7FFFFFFF;
#pragma unroll
    for (int k = t; k < 4096; k += 1024) {
        float v = dmat[k];
        if (v < best || (v == best && k < bidx)) { best = v; bidx = k; }
    }
#pragma unroll
    for (int off = 32; off > 0; off >>= 1) {
        float v2 = __shfl_xor(best, off, 64);
        int   i2 = __shfl_xor(bidx, off, 64);
        if (v2 < best || (v2 == best && i2 < bidx)) { best = v2; bidx = i2; }
    }
    if (lane == 0) { sval[wave] = best; sidx[wave] = bidx; }

    // --- bce partial sum (threads 0..127) ---
    if (t < 128) {
        float s = wave_reduce_sum(bce_part[t]);
        if (lane == 0) bpart2[wave] = s;
    }
    __syncthreads();

    if (t == 0) {
        float bv = sval[0]; int bi = sidx[0];
        for (int w = 1; w < 16; ++w)
            if (sval[w] < bv || (sval[w] == bv && sidx[w] < bi)) { bv = sval[w]; bi = sidx[w]; }
        s_mind  = bv;
        s_istar = bi >> 6;
        s_jstar = bi & 63;
        s_bce   = bpart2[0] + bpart2[1];
    }
    __syncthreads();

    // --- loss_n (waves 0..7, rows 0..63) / loss_a (waves 8..15, rows 64..127) ---
    const int  istar = s_istar, jstar = s_jstar;
    const bool is_a  = (wave >= 8);
    const int  row0  = is_a ? (BHALF + (wave - 8) * 8) : (wave * 8);
    const int  ref   = is_a ? (BHALF + jstar) : istar;
    const float* r1  = mags + (size_t)ref * NT;

    float s = 0.0f;
#pragma unroll
    for (int r = 0; r < 8; ++r) {
        const int row = row0 + r;
        if (row == ref) continue;                   // excluded star row
        const float* r0 = mags + (size_t)row * NT;
#pragma unroll
        for (int it = 0; it < 4; ++it) {
            f32x4 a = *reinterpret_cast<const f32x4*>(r0 + lane * 4 + it * 256);
            f32x4 b = *reinterpret_cast<const f32x4*>(r1 + lane * 4 + it * 256);
#pragma unroll
            for (int c = 0; c < 4; ++c) {
                float dx = a[c] - b[c] + EPS_F;
                s += dx * dx;
            }
        }
    }
    s = wave_reduce_sum(s);
    if (lane == 0) partials[wave] = s;
    __syncthreads();

    if (t == 0) {
        float ln = 0.0f, la = 0.0f;
        for (int w = 0; w < 8; ++w)  ln += partials[w];
        for (int w = 8; w < 16; ++w) la += partials[w];
        float bce      = s_bce / (float)NROWS;
        float contrast = 0.001f * s_mind + ln / (float)BHALF + la / (float)BHALF;
        out[0] = bce + 0.001f * contrast;
    }
}

extern "C" void kernel_launch(void* const* d_in, const int* in_sizes, int n_in,
                              void* d_out, int out_size, void* d_ws, size_t ws_size,
                              hipStream_t stream) {
    const float* scores  = (const float*)d_in[0];
    const float* feats   = (const float*)d_in[1];
    const float* targets = (const float*)d_in[2];
    float* out      = (float*)d_out;
    float* ws       = (float*)d_ws;
    float* bce_part = ws + 64;
    float* dmat     = ws + 1024;
    float* mags     = ws + 8192;

    mags_bce_kernel<<<MAGS_BLOCKS + BCE_BLOCKS, 256, 0, stream>>>(
        feats, scores, targets, mags, bce_part);
    dist_kernel<<<4096 / 4, 256, 0, stream>>>(mags, dmat);
    mega_kernel<<<1, 1024, 0, stream>>>(mags, dmat, bce_part, out);
}